// Round 6
// baseline (2649308.008 us; speedup 1.0000x reference)
//
#include <hip/hip_runtime.h>
#include <cstdint>
#include <cstddef>

#define TT 65536
#define KK 512
#define NEGV (-10000.0f)
#define SEG 256
#define NSEG 256  // TT/SEG

typedef unsigned short u16;
typedef unsigned int   u32;
typedef unsigned long long u64;

__device__ __forceinline__ float u2f(u32 b){ union{u32 u; float f;} x; x.u=b; return x.f; }
__device__ __forceinline__ u32 f2u(float f){ union{u32 u; float f;} x; x.f=f; return x.u; }

// ---------------------------------------------------------------------------
// Per-row sort of transitions, desc by value, asc index on ties.
// svpT[k*KK + n] (rank-major, coalesced when all rows stream rank k)
// svpR[n*KK + k] (row-major, coalesced when one wave streams one row)
// ---------------------------------------------------------------------------
__global__ __launch_bounds__(512)
void sort_rows(const float* __restrict__ trans, u64* __restrict__ svpT,
               u64* __restrict__ svpR)
{
    __shared__ u64 s[KK];
    const int n = blockIdx.x, i = threadIdx.x;
    float x = trans[n*KK + i];
    u32 b = f2u(x);
    u32 ord = (b & 0x80000000u) ? ~b : (b | 0x80000000u);   // monotone u32 order
    s[i] = ((u64)(~ord) << 16) | (u32)i;                    // asc sort => value desc, p asc
    __syncthreads();
    for (int k = 2; k <= KK; k <<= 1){
        for (int j = k >> 1; j > 0; j >>= 1){
            int ixj = i ^ j;
            if (ixj > i){
                u64 a = s[i], c = s[ixj];
                bool up = ((i & k) == 0);
                if ((a > c) == up){ s[i] = c; s[ixj] = a; }
            }
            __syncthreads();
        }
    }
    u64 key = s[i];
    u32 p    = (u32)(key & 0xFFFFu);
    u32 ordv = ~(u32)(key >> 16);
    u32 bits = (ordv & 0x80000000u) ? (ordv ^ 0x80000000u) : ~ordv;
    u64 ent = ((u64)p << 32) | bits;
    svpT[(size_t)i*KK + n] = ent;   // rank-major
    svpR[(size_t)n*KK + i] = ent;   // row-major
}

// transT[p*KK + n] = trans[n*KK + p]
__global__ __launch_bounds__(512)
void transpose_k(const float* __restrict__ t, float* __restrict__ tt)
{
    const int c = blockIdx.x, r = threadIdx.x;
    tt[(size_t)c*KK + r] = t[(size_t)r*KK + c];
}

// ---------------------------------------------------------------------------
// Phase 1: sequential VALUE-ONLY scan (1 block, 512 threads; thread i = row i).
// ONE barrier per step (fvb/wmaxS double-buffered: writes to parity [cur] at
// step t+2 are separated from step-t reads by the barrier at t+1):
//   pre : publish fv to fvb[cur]; packed (fv,idx) wave argmax -> wmaxS[cur]
//   bar : single __syncthreads()
//   post: read 8 per-wave (max,arg); fm; 8 coalesced transT warm loads
//         (best >= fl(fm + T[i, p_wave-argmax]), incl. the global argmax row);
//         prefetch svpT ranks 16..23; REG16 top-16-v eval (register cP/cV);
//         bound0: fl(fm + cV[15]) <= best -> done (zero batches, common case).
//         Else <=2 solo 8-wide coalesced svpT batches with exact bound
//         fl(fm + v_last) <= best; still-pending rows -> wave-cooperative
//         svpR streaming from rank 32 (64 ranks/chunk, shfl-reduce), bound
//         fl(fm + v_chunk_last) <= bestR.
// Exactness: every candidate is fl(fv_p + trans[i,p]); any unevaluated p at a
// bound has v <= v_last and fv <= fm -> fl(fv+v) <= fl(fm+v_last) <= best
// (monotone fl). Row 1 (all-NEG): warm start yields exactly fl(fm+NEG) and
// bound0 is an equality -> done immediately.
// Stores fm per step and boundary states every SEG steps for bp_fill.
// ---------------------------------------------------------------------------
__global__ __launch_bounds__(512)
void fv_scan(const float* __restrict__ feats,
             const u64* __restrict__ svpT,
             const u64* __restrict__ svpR,
             const float* __restrict__ transT,
             float* __restrict__ fvBound,
             float* __restrict__ fmArr,
             float* __restrict__ outScore, int* __restrict__ bestOut)
{
    __shared__ float fvb[2][KK];
    __shared__ u64  wmaxS[2][8];
    __shared__ float rv[KK];
    __shared__ int   ri[KK];

    const int i = threadIdx.x, lane = i & 63, wv = i >> 6;

    // top-16 (v,p) of own row in registers
    float cV[16]; int cP[16];
#pragma unroll
    for (int k = 0; k < 16; ++k){
        u64 e = svpT[(size_t)k*KK + i];
        cV[k] = u2f((u32)e); cP[k] = (int)(e >> 32);
    }
    const float cv15 = cV[15];

    // step 0 closed form: fv_init = [0, NEG..]; col 0 of trans == NEG exactly
    float fv_i = fmaxf(NEGV, NEGV + cV[0]) + feats[i];
    fvBound[i] = fv_i;                       // state(1) = segment-0 start
    float featCur = feats[(size_t)KK + i];

#define VMAX8(k0) { \
    float f0=fvc[cP[k0]],     f1=fvc[cP[(k0)+1]], f2=fvc[cP[(k0)+2]], f3=fvc[cP[(k0)+3]]; \
    float f4=fvc[cP[(k0)+4]], f5=fvc[cP[(k0)+5]], f6=fvc[cP[(k0)+6]], f7=fvc[cP[(k0)+7]]; \
    float m0=fmaxf(f0+cV[k0],     f1+cV[(k0)+1]), m1=fmaxf(f2+cV[(k0)+2], f3+cV[(k0)+3]); \
    float m2=fmaxf(f4+cV[(k0)+4], f5+cV[(k0)+5]), m3=fmaxf(f6+cV[(k0)+6], f7+cV[(k0)+7]); \
    best = fmaxf(best, fmaxf(fmaxf(m0,m1), fmaxf(m2,m3))); }

// evaluate 8 svpT entries E_[0..7] (p in high 32, v-bits in low 32)
#define EVSVP(E_) { \
    int _p0=(int)((E_)[0]>>32), _p1=(int)((E_)[1]>>32); \
    int _p2=(int)((E_)[2]>>32), _p3=(int)((E_)[3]>>32); \
    int _p4=(int)((E_)[4]>>32), _p5=(int)((E_)[5]>>32); \
    int _p6=(int)((E_)[6]>>32), _p7=(int)((E_)[7]>>32); \
    float _f0=fvc[_p0], _f1=fvc[_p1], _f2=fvc[_p2], _f3=fvc[_p3]; \
    float _f4=fvc[_p4], _f5=fvc[_p5], _f6=fvc[_p6], _f7=fvc[_p7]; \
    float _m0=fmaxf(_f0+u2f((u32)(E_)[0]), _f1+u2f((u32)(E_)[1])); \
    float _m1=fmaxf(_f2+u2f((u32)(E_)[2]), _f3+u2f((u32)(E_)[3])); \
    float _m2=fmaxf(_f4+u2f((u32)(E_)[4]), _f5+u2f((u32)(E_)[5])); \
    float _m3=fmaxf(_f6+u2f((u32)(E_)[6]), _f7+u2f((u32)(E_)[7])); \
    best = fmaxf(best, fmaxf(fmaxf(_m0,_m1), fmaxf(_m2,_m3))); }

    for (int t = 1; t < TT; ++t){
        const int cur = t & 1;

        // ---------- publish fv + packed (fv,idx) wave argmax ----------
        fvb[cur][i] = fv_i;
        {
            u32 ob = f2u(fv_i);
            ob = (ob & 0x80000000u) ? ~ob : (ob | 0x80000000u);
            u64 key = ((u64)ob << 32) | (u32)i;
#pragma unroll
            for (int o = 32; o > 0; o >>= 1){
                u64 ok = __shfl_xor(key, o, 64);
                key = (ok > key) ? ok : key;
            }
            if (lane == 0) wmaxS[cur][wv] = key;
        }
        __syncthreads();                         // the ONLY barrier per step

        // ---------- per-wave (max,arg) -> fm + 8-row transT warm start ------
        float wmv[8], pfv[8];
#pragma unroll
        for (int w = 0; w < 8; ++w){
            u64 kw = wmaxS[cur][w];
            u32 ov = (u32)(kw >> 32);
            u32 bits = (ov & 0x80000000u) ? (ov ^ 0x80000000u) : ~ov;
            wmv[w] = u2f(bits);
            int pw = __builtin_amdgcn_readfirstlane((int)(u32)kw);
            pfv[w] = transT[(size_t)pw*KK + i];              // coalesced, issued early
        }
        float fm = wmv[0];
#pragma unroll
        for (int w = 1; w < 8; ++w) fm = fmaxf(fm, wmv[w]);
        if (i == 0) fmArr[t] = fm;

        // prefetch solo batch 1 (ranks 16..23) before knowing if it's needed
        u64 Ea[8];
#pragma unroll
        for (int j = 0; j < 8; ++j) Ea[j] = svpT[(size_t)(16+j)*KK + i];

        const float* fvc = fvb[cur];
        float featNxt = __builtin_nontemporal_load(
            &feats[(size_t)(t+1 < TT ? t+1 : t)*KK + i]);

        float best = -3.0e38f;
        VMAX8(0) VMAX8(8)
#pragma unroll
        for (int w = 0; w < 8; ++w) best = fmaxf(best, wmv[w] + pfv[w]);

        // ---------- bound ladder ----------
        bool done = (fm + cv15 <= best);          // covers all ranks >= 16
        if (__any(!done)){
            if (!done){
                EVSVP(Ea)
                float vlast = u2f((u32)Ea[7]);    // v at rank 23
                done = (fm + vlast <= best);
            }
            if (__any(!done)){
                if (!done){
                    u64 Eb[8];
#pragma unroll
                    for (int j = 0; j < 8; ++j) Eb[j] = svpT[(size_t)(24+j)*KK + i];
                    EVSVP(Eb)
                    float vlast = u2f((u32)Eb[7]); // v at rank 31
                    done = (fm + vlast <= best);
                }
                // ---------- wave-cooperative tail from rank 32 ----------
                // pending rows have evaluated ranks 0..31 exactly
                u64 pend = __ballot(!done);
                while (pend){
                    int r = (int)__ffsll((unsigned long long)pend) - 1;
                    pend &= pend - 1;
                    const int row = (wv << 6) + r;
                    float bestR = __shfl(best, r, 64);
                    int rk = 32 + lane;
                    for (;;){
                        float vv = -1.0e30f, sc = -1.0e30f;
                        if (rk < KK){
                            u64 e = svpR[(size_t)row*KK + rk];
                            vv = u2f((u32)e);
                            sc = fvc[(int)(e >> 32)] + vv;
                        }
                        float m = sc;
#pragma unroll
                        for (int o = 32; o > 0; o >>= 1) m = fmaxf(m, __shfl_xor(m, o, 64));
                        bestR = fmaxf(bestR, m);
                        float vl = __shfl(vv, 63, 64);   // smallest v this chunk
                        if (fm + vl <= bestR) break;      // uniform break (OOB => -1e30)
                        rk += 64;
                    }
                    if (lane == r) best = bestR;
                }
            }
        }

        // ---------- finish step ----------
        fv_i = best + featCur;
        featCur = featNxt;
        if ((t & (SEG-1)) == 0)
            fvBound[(size_t)(t >> 8)*KK + i] = fv_i;  // state(t+1)
    }
#undef VMAX8
#undef EVSVP

    // ---- terminal: terminal[p] = fl(fv_T[p] + NEG); first-index argmax ----
    float tv = fv_i + NEGV;
    rv[i] = tv; ri[i] = i;
    __syncthreads();
    for (int s2r = 256; s2r > 0; s2r >>= 1){
        if (i < s2r){
            float v2 = rv[i+s2r]; int i2 = ri[i+s2r];
            if (v2 > rv[i] || (v2 == rv[i] && i2 < ri[i])){ rv[i] = v2; ri[i] = i2; }
        }
        __syncthreads();
    }
    if (i == 0){ outScore[0] = rv[0]; *bestOut = ri[0]; }
}

// ---------------------------------------------------------------------------
// Phase 2: parallel backpointer fill. Block s re-runs segment s (SEG steps)
// from the stored boundary state (bit-exact) and computes bp[t][i] with
// reference-exact first-index-tie argmax: rank-scan svpT with strict bound
// fl(fm + v_next) < best (continue on equality => ties never skipped).
// Row 1 (all v == NEG) special-cased exactly: max = fl(fm+NEG); argmax =
// first-index argmax of ROUNDED fl(fv[p]+NEG) via block reduce, min-index tie.
// ---------------------------------------------------------------------------
__global__ __launch_bounds__(512)
void bp_fill(const float* __restrict__ feats,
             const u64* __restrict__ svpT,
             const float* __restrict__ fvBound,
             const float* __restrict__ fmArr,
             u16* __restrict__ bp)
{
    __shared__ float fvb[2][KK];
    __shared__ u64  r1S[2][8];
    const int i = threadIdx.x, lane = i & 63, wv = i >> 6;
    const int s = blockIdx.x;
    const int t0 = s*SEG + 1;
    const int tEnd = (s == NSEG-1) ? (TT-1) : (s*SEG + SEG);

    float fv_i = fvBound[(size_t)s*KK + i];
    float featC = feats[(size_t)t0*KK + i];

#define TAKE(p_, val_) { float _val=(val_); int _p=(p_); \
    bool _tk = (_val > best) || (_val == best && _p < barg); \
    best = _tk ? _val : best; barg = _tk ? _p : barg; }

    for (int t = t0; t <= tEnd; ++t){
        const int cur = t & 1;
        fvb[cur][i] = fv_i;
        // row-1 argmax key: rounded score fl(fv+NEG), min-p tie -> max key
        float sc1 = fv_i + NEGV;
        u32 bb = f2u(sc1);
        u32 od = (bb & 0x80000000u) ? ~bb : (bb | 0x80000000u);
        u64 key = ((u64)od << 32) | (u32)(KK - 1 - i);
#pragma unroll
        for (int o = 32; o > 0; o >>= 1){
            u64 ok = __shfl_xor(key, o, 64);
            key = (ok > key) ? ok : key;
        }
        if (lane == 0) r1S[cur][wv] = key;
        float featN = (t < tEnd) ? feats[(size_t)(t+1)*KK + i] : 0.0f;
        __syncthreads();
        const float fm = fmArr[t];
        const float* fvc = fvb[cur];
        float best; int barg;
        if (i == 1){
            u64 kk = r1S[cur][0];
#pragma unroll
            for (int w = 1; w < 8; ++w){ u64 o2 = r1S[cur][w]; kk = (o2 > kk) ? o2 : kk; }
            barg = (KK - 1) - (int)(u32)kk;
            best = fm + NEGV;
        } else {
            best = -3.0e38f; barg = 0;
            for (int kb = 0; kb < KK; kb += 8){
                const u64* sp = &svpT[(size_t)kb*KK + i];
                u64 E0 = sp[0];          u64 E1 = sp[(size_t)KK];
                u64 E2 = sp[(size_t)2*KK]; u64 E3 = sp[(size_t)3*KK];
                u64 E4 = sp[(size_t)4*KK]; u64 E5 = sp[(size_t)5*KK];
                u64 E6 = sp[(size_t)6*KK]; u64 E7 = sp[(size_t)7*KK];
                int p0=(int)(E0>>32), p1=(int)(E1>>32), p2=(int)(E2>>32), p3=(int)(E3>>32);
                int p4=(int)(E4>>32), p5=(int)(E5>>32), p6=(int)(E6>>32), p7=(int)(E7>>32);
                TAKE(p0, fvc[p0] + u2f((u32)E0)); TAKE(p1, fvc[p1] + u2f((u32)E1));
                TAKE(p2, fvc[p2] + u2f((u32)E2)); TAKE(p3, fvc[p3] + u2f((u32)E3));
                TAKE(p4, fvc[p4] + u2f((u32)E4)); TAKE(p5, fvc[p5] + u2f((u32)E5));
                TAKE(p6, fvc[p6] + u2f((u32)E6)); TAKE(p7, fvc[p7] + u2f((u32)E7));
                float vlast = u2f((u32)E7);
                if (fm + vlast < best) break;   // strict: equality could tie later
            }
        }
        __builtin_nontemporal_store((u16)barg, &bp[(size_t)t*KK + i]);
        fv_i = best + featC;
        featC = featN;
    }
#undef TAKE
}

// ---------------------------------------------------------------------------
// Backtrack: segment maps (parallel) -> boundary tags -> per-segment decode.
// ---------------------------------------------------------------------------
__global__ __launch_bounds__(512)
void bt_maps(const u16* __restrict__ bp, u16* __restrict__ maps)
{
    const int s = blockIdx.x, e = threadIdx.x;
    const int tEnd = (s == NSEG-1) ? (TT-1) : (s+1)*SEG;
    const int tLow = s*SEG;
    int cur = e;
    for (int t = tEnd; t > tLow; --t) cur = (int)bp[(size_t)t*KK + cur];
    maps[s*KK + e] = (u16)cur;
}

__global__ void bt_boundaries(const u16* __restrict__ maps, const int* __restrict__ bestP,
                              int* __restrict__ btag)
{
    if (threadIdx.x != 0 || blockIdx.x != 0) return;
    int cur = *bestP;
    for (int s = NSEG-1; s >= 0; --s){
        cur = (int)maps[s*KK + cur];
        btag[s] = cur;
    }
}

__global__ void bt_decode(const u16* __restrict__ bp, const int* __restrict__ btag,
                          const int* __restrict__ bestP, float* __restrict__ outPath)
{
    const int s = blockIdx.x;
    if (threadIdx.x != 0) return;
    int tEnd, cur;
    if (s == NSEG-1){ tEnd = TT-1; cur = *bestP; outPath[TT-1] = (float)cur; }
    else            { tEnd = (s+1)*SEG; cur = btag[s+1]; }
    for (int t = tEnd; t > s*SEG; --t){
        cur = (int)bp[(size_t)t*KK + cur];
        outPath[t-1] = (float)cur;
    }
}

// ---------------------------------------------------------------------------
extern "C" void kernel_launch(void* const* d_in, const int* in_sizes, int n_in,
                              void* d_out, int out_size, void* d_ws, size_t ws_size,
                              hipStream_t stream)
{
    (void)in_sizes; (void)n_in; (void)out_size; (void)ws_size;
    const float* feats = (const float*)d_in[0];
    const float* trans = (const float*)d_in[1];
    float* out = (float*)d_out;

    char* ws = (char*)d_ws;
    size_t off = 0;
    u16*   bp     = (u16*)(ws + off);   off += (size_t)TT*KK*sizeof(u16);    // 64 MB
    u64*   svpT   = (u64*)(ws + off);   off += (size_t)KK*KK*sizeof(u64);    // 2 MB
    u64*   svpR   = (u64*)(ws + off);   off += (size_t)KK*KK*sizeof(u64);    // 2 MB
    float* transT = (float*)(ws + off); off += (size_t)KK*KK*sizeof(float);  // 1 MB
    float* fvBound= (float*)(ws + off); off += (size_t)NSEG*KK*sizeof(float);// 512 KB
    float* fmArr  = (float*)(ws + off); off += (size_t)TT*sizeof(float);     // 256 KB
    u16*   maps   = (u16*)(ws + off);   off += (size_t)NSEG*KK*sizeof(u16);  // 256 KB
    int*   btag   = (int*)(ws + off);   off += (size_t)(NSEG+8)*sizeof(int);
    int*   bestP  = (int*)(ws + off);

    hipLaunchKernelGGL(sort_rows,     dim3(KK),   dim3(512), 0, stream, trans, svpT, svpR);
    hipLaunchKernelGGL(transpose_k,   dim3(KK),   dim3(512), 0, stream, trans, transT);
    hipLaunchKernelGGL(fv_scan,       dim3(1),    dim3(512), 0, stream, feats, svpT, svpR,
                       transT, fvBound, fmArr, out, bestP);
    hipLaunchKernelGGL(bp_fill,       dim3(NSEG), dim3(512), 0, stream, feats, svpT,
                       fvBound, fmArr, bp);
    hipLaunchKernelGGL(bt_maps,       dim3(NSEG), dim3(512), 0, stream, bp, maps);
    hipLaunchKernelGGL(bt_boundaries, dim3(1),    dim3(64),  0, stream, maps, bestP, btag);
    hipLaunchKernelGGL(bt_decode,     dim3(NSEG), dim3(64),  0, stream, bp, btag, bestP, out + 1);
}

// Round 7
// 308302.466 us; speedup vs baseline: 8.5932x; 8.5932x over previous
//
#include <hip/hip_runtime.h>
#include <cstdint>
#include <cstddef>

#define TT 65536
#define KK 512
#define NEGV (-10000.0f)
#define SEG 256
#define NSEG 256  // TT/SEG
#define RK 48     // register top-K by transition value

typedef unsigned short u16;
typedef unsigned int   u32;
typedef unsigned long long u64;

__device__ __forceinline__ float u2f(u32 b){ union{u32 u; float f;} x; x.u=b; return x.f; }
__device__ __forceinline__ u32 f2u(float f){ union{u32 u; float f;} x; x.f=f; return x.u; }

// ---------------------------------------------------------------------------
// Per-row sort of transitions, desc by value, asc index on ties.
// svpT[k*KK + n] (rank-major, coalesced when all rows stream rank k)
// ---------------------------------------------------------------------------
__global__ __launch_bounds__(512)
void sort_rows(const float* __restrict__ trans, u64* __restrict__ svpT)
{
    __shared__ u64 s[KK];
    const int n = blockIdx.x, i = threadIdx.x;
    float x = trans[n*KK + i];
    u32 b = f2u(x);
    u32 ord = (b & 0x80000000u) ? ~b : (b | 0x80000000u);   // monotone u32 order
    s[i] = ((u64)(~ord) << 16) | (u32)i;                    // asc sort => value desc, p asc
    __syncthreads();
    for (int k = 2; k <= KK; k <<= 1){
        for (int j = k >> 1; j > 0; j >>= 1){
            int ixj = i ^ j;
            if (ixj > i){
                u64 a = s[i], c = s[ixj];
                bool up = ((i & k) == 0);
                if ((a > c) == up){ s[i] = c; s[ixj] = a; }
            }
            __syncthreads();
        }
    }
    u64 key = s[i];
    u32 p    = (u32)(key & 0xFFFFu);
    u32 ordv = ~(u32)(key >> 16);
    u32 bits = (ordv & 0x80000000u) ? (ordv ^ 0x80000000u) : ~ordv;
    svpT[(size_t)i*KK + n] = ((u64)p << 32) | bits;   // rank-major
}

// transT[p*KK + n] = trans[n*KK + p]
__global__ __launch_bounds__(512)
void transpose_k(const float* __restrict__ t, float* __restrict__ tt)
{
    const int c = blockIdx.x, r = threadIdx.x;
    tt[(size_t)c*KK + r] = t[(size_t)r*KK + c];
}

// ---------------------------------------------------------------------------
// Phase 1: sequential VALUE-ONLY scan (1 block, 512 threads; thread i = row i).
// R1 skeleton (3 barriers, ballot+prefix compaction, batch-8 band eval,
// lockstep rank tail) + tighter certificate:
//   pre-A : publish fv; packed (fv,idx) wave argmax -> wmaxS
//   A     : decode 8 per-wave (max,arg); fm; ISSUE 8 coalesced transT warm
//           loads (raises best to >= fl(fm+T[i,p*]) incl. global argmax row);
//           6 band ballots (fm-0.5..fm-3.0), lane0 -> masks+counts;
//           overlap: REG48 top-48-v eval + warm consume
//   B     : cross-wave prefix compaction -> dense band-major bandE; sentinels
//   C     : pre-bound fm+cv47<=best (skip all bands); else per-band batch-8
//           eval (broadcast bandE + coalesced transT), bound edge+cv47<=best.
//           Rare tail: lockstep svpT rank stream from RK, bound e5+vlast<=best.
// Certificate: unevaluated p has fv <= edge (bands complete above edge) and
// v <= cV[RK-1] (top-RK by v evaluated in registers) -> fl(fv+v) <=
// fl(edge+cv47) <= best by monotone fl. Value-only max: ties can't raise it.
// Row 1 (all-NEG): warm start yields exactly fl(fm+NEG); pre/band-0 bound
// closes it immediately.
// Stores fm per step and boundary states every SEG steps for bp_fill.
// ---------------------------------------------------------------------------
__global__ __launch_bounds__(512)
void fv_scan(const float* __restrict__ feats,
             const u64* __restrict__ svpT,
             const float* __restrict__ transT,
             float* __restrict__ fvBound,
             float* __restrict__ fmArr,
             float* __restrict__ outScore, int* __restrict__ bestOut)
{
    __shared__ float fvb[2][KK];
    __shared__ u64  wmaxS[2][8];
    __shared__ u64  bmS[6][8];     // [band][wave] membership masks
    __shared__ u32  cntS[6][8];    // [band][wave] popcounts
    __shared__ u64  bandE[KK + 8]; // dense band-major candidate list + sentinels
    __shared__ float rv[KK];
    __shared__ int   ri[KK];

    const int i = threadIdx.x, lane = i & 63, wv = i >> 6;
    const u64 laneLT = (1ull << lane) - 1ull;

    // top-RK (v,p) of own row in registers
    float cV[RK]; int cP[RK];
#pragma unroll
    for (int k = 0; k < RK; ++k){
        u64 e = svpT[(size_t)k*KK + i];
        cV[k] = u2f((u32)e); cP[k] = (int)(e >> 32);
    }
    const float cvK = cV[RK-1];

    // step 0 closed form: fv_init = [0, NEG..]; col 0 of trans == NEG exactly
    float fv_i = fmaxf(NEGV, NEGV + cV[0]) + feats[i];
    fvBound[i] = fv_i;                       // state(1) = segment-0 start
    float featCur = feats[(size_t)KK + i];

#define VMAX8(k0) { \
    float f0=fvc[cP[k0]],     f1=fvc[cP[(k0)+1]], f2=fvc[cP[(k0)+2]], f3=fvc[cP[(k0)+3]]; \
    float f4=fvc[cP[(k0)+4]], f5=fvc[cP[(k0)+5]], f6=fvc[cP[(k0)+6]], f7=fvc[cP[(k0)+7]]; \
    float m0=fmaxf(f0+cV[k0],     f1+cV[(k0)+1]), m1=fmaxf(f2+cV[(k0)+2], f3+cV[(k0)+3]); \
    float m2=fmaxf(f4+cV[(k0)+4], f5+cV[(k0)+5]), m3=fmaxf(f6+cV[(k0)+6], f7+cV[(k0)+7]); \
    best = fmaxf(best, fmaxf(fmaxf(m0,m1), fmaxf(m2,m3))); }

    for (int t = 1; t < TT; ++t){
        const int cur = t & 1;

        // ---------- publish fv + packed (fv,idx) wave argmax ----------
        fvb[cur][i] = fv_i;
        {
            u32 ob = f2u(fv_i);
            ob = (ob & 0x80000000u) ? ~ob : (ob | 0x80000000u);
            u64 key = ((u64)ob << 32) | (u32)i;
#pragma unroll
            for (int o = 32; o > 0; o >>= 1){
                u64 ok = __shfl_xor(key, o, 64);
                key = (ok > key) ? ok : key;
            }
            if (lane == 0) wmaxS[cur][wv] = key;
        }
        __syncthreads();                                     // A

        // ---------- per-wave (max,arg) -> fm + 8-row transT warm start ------
        float wmv[8], pfv[8];
#pragma unroll
        for (int w = 0; w < 8; ++w){
            u64 kw = wmaxS[cur][w];
            u32 ov = (u32)(kw >> 32);
            u32 bits = (ov & 0x80000000u) ? (ov ^ 0x80000000u) : ~ov;
            wmv[w] = u2f(bits);
            int pw = __builtin_amdgcn_readfirstlane((int)(u32)kw);
            pfv[w] = transT[(size_t)pw*KK + i];              // coalesced, issued early
        }
        float fm = wmv[0];
#pragma unroll
        for (int w = 1; w < 8; ++w) fm = fmaxf(fm, wmv[w]);
        if (i == 0) fmArr[t] = fm;

        // ---------- 6 band ballots -> per-wave masks + counts ----------
        const float e0=fm-0.5f, e1=fm-1.0f, e2=fm-1.5f,
                    e3=fm-2.0f, e4=fm-2.5f, e5=fm-3.0f;
        u64 q0 = __ballot(fv_i > e0), q1 = __ballot(fv_i > e1);
        u64 q2 = __ballot(fv_i > e2), q3 = __ballot(fv_i > e3);
        u64 q4 = __ballot(fv_i > e4), q5 = __ballot(fv_i > e5);
        if (lane == 0){
            u64 b0=q0, b1=q1&~q0, b2=q2&~q1, b3=q3&~q2, b4=q4&~q3, b5=q5&~q4;
            bmS[0][wv]=b0; cntS[0][wv]=(u32)__builtin_popcountll(b0);
            bmS[1][wv]=b1; cntS[1][wv]=(u32)__builtin_popcountll(b1);
            bmS[2][wv]=b2; cntS[2][wv]=(u32)__builtin_popcountll(b2);
            bmS[3][wv]=b3; cntS[3][wv]=(u32)__builtin_popcountll(b3);
            bmS[4][wv]=b4; cntS[4][wv]=(u32)__builtin_popcountll(b4);
            bmS[5][wv]=b5; cntS[5][wv]=(u32)__builtin_popcountll(b5);
        }

        // ---------- overlapped: REG48 + warm-start consume ----------
        const float* fvc = fvb[cur];
        float featNxt = __builtin_nontemporal_load(
            &feats[(size_t)(t+1 < TT ? t+1 : t)*KK + i]);
        float best = -3.0e38f;
        VMAX8(0) VMAX8(8) VMAX8(16) VMAX8(24) VMAX8(32) VMAX8(40)
#pragma unroll
        for (int w = 0; w < 8; ++w) best = fmaxf(best, wmv[w] + pfv[w]);
        __syncthreads();                                     // B

        // ---------- prefix compaction into dense band-major list ----------
        u32 tot0=0, tot1=0, tot2=0, tot3=0, tot4=0, tot5=0;
#pragma unroll
        for (int w = 0; w < 8; ++w){
            tot0 += cntS[0][w]; tot1 += cntS[1][w]; tot2 += cntS[2][w];
            tot3 += cntS[3][w]; tot4 += cntS[4][w]; tot5 += cntS[5][w];
        }
        int b_i = (fv_i > e0)?0:(fv_i > e1)?1:(fv_i > e2)?2:
                  (fv_i > e3)?3:(fv_i > e4)?4:(fv_i > e5)?5:6;
        if (b_i < 6){
            u32 off = (b_i > 0 ? tot0 : 0u) + (b_i > 1 ? tot1 : 0u) +
                      (b_i > 2 ? tot2 : 0u) + (b_i > 3 ? tot3 : 0u) +
                      (b_i > 4 ? tot4 : 0u);
#pragma unroll
            for (int w = 0; w < 8; ++w) off += (w < wv) ? cntS[b_i][w] : 0u;
            off += (u32)__builtin_popcountll(bmS[b_i][wv] & laneLT);
            bandE[off] = ((u64)f2u(fv_i) << 32) | (u32)i;
        }
        u32 totAll = tot0+tot1+tot2+tot3+tot4+tot5;
        if (i < 8) bandE[totAll + i] = ((u64)f2u(-1.0e30f) << 32);
        int s0 = __builtin_amdgcn_readfirstlane((int)tot0);
        int s1 = __builtin_amdgcn_readfirstlane((int)tot1);
        int s2 = __builtin_amdgcn_readfirstlane((int)tot2);
        int s3 = __builtin_amdgcn_readfirstlane((int)tot3);
        int s4 = __builtin_amdgcn_readfirstlane((int)tot4);
        int s5 = __builtin_amdgcn_readfirstlane((int)tot5);
        __syncthreads();                                     // C

        // ---------- band eval: pre-bound, then per-band batch-8 ----------
        bool done = (fm + cvK <= best);   // covers all p outside top-RK
        int base = 0;
#pragma unroll 1
        for (int b = 0; b < 6; ++b){
            const int  cntb = (b==0)?s0:(b==1)?s1:(b==2)?s2:(b==3)?s3:(b==4)?s4:s5;
            const float edge = fm - 0.5f*(float)(b+1);
            if (!__any(!done)) break;
            if (!done && cntb > 0){
                for (int u = 0; u < cntb; u += 8){
                    const int jj = base + u;
                    u64 E0=bandE[jj],   E1=bandE[jj+1], E2=bandE[jj+2], E3=bandE[jj+3];
                    u64 E4=bandE[jj+4], E5=bandE[jj+5], E6=bandE[jj+6], E7=bandE[jj+7];
                    int p0=(int)(E0&0xFFFFu), p1=(int)(E1&0xFFFFu);
                    int p2=(int)(E2&0xFFFFu), p3=(int)(E3&0xFFFFu);
                    int p4=(int)(E4&0xFFFFu), p5=(int)(E5&0xFFFFu);
                    int p6=(int)(E6&0xFFFFu), p7=(int)(E7&0xFFFFu);
                    float t0=transT[(size_t)p0*KK+i], t1=transT[(size_t)p1*KK+i];
                    float t2=transT[(size_t)p2*KK+i], t3=transT[(size_t)p3*KK+i];
                    float t4=transT[(size_t)p4*KK+i], t5=transT[(size_t)p5*KK+i];
                    float t6=transT[(size_t)p6*KK+i], t7=transT[(size_t)p7*KK+i];
                    float a0=u2f((u32)(E0>>32))+t0, a1=u2f((u32)(E1>>32))+t1;
                    float a2=u2f((u32)(E2>>32))+t2, a3=u2f((u32)(E3>>32))+t3;
                    float a4=u2f((u32)(E4>>32))+t4, a5=u2f((u32)(E5>>32))+t5;
                    float a6=u2f((u32)(E6>>32))+t6, a7=u2f((u32)(E7>>32))+t7;
                    best = fmaxf(best,
                           fmaxf(fmaxf(fmaxf(a0,a1),fmaxf(a2,a3)),
                                 fmaxf(fmaxf(a4,a5),fmaxf(a6,a7))));
                }
            }
            done = done || (edge + cvK <= best);
            base += cntb;
        }

        // ---------- rare tail: lockstep rank-major stream, exact bound ------
        // pending rows: all p with fv > e5 evaluated; ranks 0..RK-1 evaluated.
        int kc = RK;
        while (__any(!done) && kc < KK){
            if (!done){
                float vlast = NEGV;
#pragma unroll
                for (int j2 = 0; j2 < 8; ++j2){
                    u64 e = svpT[(size_t)(kc+j2)*KK + i];
                    float vv = u2f((u32)e); int pp = (int)(e >> 32);
                    best = fmaxf(best, fvc[pp] + vv);
                    vlast = vv;
                }
                done = (e5 + vlast <= best);
            }
            kc += 8;
        }

        // ---------- finish step ----------
        fv_i = best + featCur;
        featCur = featNxt;
        if ((t & (SEG-1)) == 0)
            fvBound[(size_t)(t >> 8)*KK + i] = fv_i;  // state(t+1)
    }
#undef VMAX8

    // ---- terminal: terminal[p] = fl(fv_T[p] + NEG); first-index argmax ----
    float tv = fv_i + NEGV;
    rv[i] = tv; ri[i] = i;
    __syncthreads();
    for (int s2r = 256; s2r > 0; s2r >>= 1){
        if (i < s2r){
            float v2 = rv[i+s2r]; int i2 = ri[i+s2r];
            if (v2 > rv[i] || (v2 == rv[i] && i2 < ri[i])){ rv[i] = v2; ri[i] = i2; }
        }
        __syncthreads();
    }
    if (i == 0){ outScore[0] = rv[0]; *bestOut = ri[0]; }
}

// ---------------------------------------------------------------------------
// Phase 2: parallel backpointer fill. Block s re-runs segment s (SEG steps)
// from the stored boundary state (bit-exact) and computes bp[t][i] with
// reference-exact first-index-tie argmax: rank-scan svpT with strict bound
// fl(fm + v_next) < best (continue on equality => ties never skipped).
// Row 1 (all v == NEG) special-cased exactly: max = fl(fm+NEG); argmax =
// first-index argmax of ROUNDED fl(fv[p]+NEG) via block reduce, min-index tie.
// ---------------------------------------------------------------------------
__global__ __launch_bounds__(512)
void bp_fill(const float* __restrict__ feats,
             const u64* __restrict__ svpT,
             const float* __restrict__ fvBound,
             const float* __restrict__ fmArr,
             u16* __restrict__ bp)
{
    __shared__ float fvb[2][KK];
    __shared__ u64  r1S[2][8];
    const int i = threadIdx.x, lane = i & 63, wv = i >> 6;
    const int s = blockIdx.x;
    const int t0 = s*SEG + 1;
    const int tEnd = (s == NSEG-1) ? (TT-1) : (s*SEG + SEG);

    float fv_i = fvBound[(size_t)s*KK + i];
    float featC = feats[(size_t)t0*KK + i];

#define TAKE(p_, val_) { float _val=(val_); int _p=(p_); \
    bool _tk = (_val > best) || (_val == best && _p < barg); \
    best = _tk ? _val : best; barg = _tk ? _p : barg; }

    for (int t = t0; t <= tEnd; ++t){
        const int cur = t & 1;
        fvb[cur][i] = fv_i;
        // row-1 argmax key: rounded score fl(fv+NEG), min-p tie -> max key
        float sc1 = fv_i + NEGV;
        u32 bb = f2u(sc1);
        u32 od = (bb & 0x80000000u) ? ~bb : (bb | 0x80000000u);
        u64 key = ((u64)od << 32) | (u32)(KK - 1 - i);
#pragma unroll
        for (int o = 32; o > 0; o >>= 1){
            u64 ok = __shfl_xor(key, o, 64);
            key = (ok > key) ? ok : key;
        }
        if (lane == 0) r1S[cur][wv] = key;
        float featN = (t < tEnd) ? feats[(size_t)(t+1)*KK + i] : 0.0f;
        __syncthreads();
        const float fm = fmArr[t];
        const float* fvc = fvb[cur];
        float best; int barg;
        if (i == 1){
            u64 kk = r1S[cur][0];
#pragma unroll
            for (int w = 1; w < 8; ++w){ u64 o2 = r1S[cur][w]; kk = (o2 > kk) ? o2 : kk; }
            barg = (KK - 1) - (int)(u32)kk;
            best = fm + NEGV;
        } else {
            best = -3.0e38f; barg = 0;
            for (int kb = 0; kb < KK; kb += 8){
                const u64* sp = &svpT[(size_t)kb*KK + i];
                u64 E0 = sp[0];          u64 E1 = sp[(size_t)KK];
                u64 E2 = sp[(size_t)2*KK]; u64 E3 = sp[(size_t)3*KK];
                u64 E4 = sp[(size_t)4*KK]; u64 E5 = sp[(size_t)5*KK];
                u64 E6 = sp[(size_t)6*KK]; u64 E7 = sp[(size_t)7*KK];
                int p0=(int)(E0>>32), p1=(int)(E1>>32), p2=(int)(E2>>32), p3=(int)(E3>>32);
                int p4=(int)(E4>>32), p5=(int)(E5>>32), p6=(int)(E6>>32), p7=(int)(E7>>32);
                TAKE(p0, fvc[p0] + u2f((u32)E0)); TAKE(p1, fvc[p1] + u2f((u32)E1));
                TAKE(p2, fvc[p2] + u2f((u32)E2)); TAKE(p3, fvc[p3] + u2f((u32)E3));
                TAKE(p4, fvc[p4] + u2f((u32)E4)); TAKE(p5, fvc[p5] + u2f((u32)E5));
                TAKE(p6, fvc[p6] + u2f((u32)E6)); TAKE(p7, fvc[p7] + u2f((u32)E7));
                float vlast = u2f((u32)E7);
                if (fm + vlast < best) break;   // strict: equality could tie later
            }
        }
        __builtin_nontemporal_store((u16)barg, &bp[(size_t)t*KK + i]);
        fv_i = best + featC;
        featC = featN;
    }
#undef TAKE
}

// ---------------------------------------------------------------------------
// Backtrack: segment maps (parallel) -> boundary tags -> per-segment decode.
// ---------------------------------------------------------------------------
__global__ __launch_bounds__(512)
void bt_maps(const u16* __restrict__ bp, u16* __restrict__ maps)
{
    const int s = blockIdx.x, e = threadIdx.x;
    const int tEnd = (s == NSEG-1) ? (TT-1) : (s+1)*SEG;
    const int tLow = s*SEG;
    int cur = e;
    for (int t = tEnd; t > tLow; --t) cur = (int)bp[(size_t)t*KK + cur];
    maps[s*KK + e] = (u16)cur;
}

__global__ void bt_boundaries(const u16* __restrict__ maps, const int* __restrict__ bestP,
                              int* __restrict__ btag)
{
    if (threadIdx.x != 0 || blockIdx.x != 0) return;
    int cur = *bestP;
    for (int s = NSEG-1; s >= 0; --s){
        cur = (int)maps[s*KK + cur];
        btag[s] = cur;
    }
}

__global__ void bt_decode(const u16* __restrict__ bp, const int* __restrict__ btag,
                          const int* __restrict__ bestP, float* __restrict__ outPath)
{
    const int s = blockIdx.x;
    if (threadIdx.x != 0) return;
    int tEnd, cur;
    if (s == NSEG-1){ tEnd = TT-1; cur = *bestP; outPath[TT-1] = (float)cur; }
    else            { tEnd = (s+1)*SEG; cur = btag[s+1]; }
    for (int t = tEnd; t > s*SEG; --t){
        cur = (int)bp[(size_t)t*KK + cur];
        outPath[t-1] = (float)cur;
    }
}

// ---------------------------------------------------------------------------
extern "C" void kernel_launch(void* const* d_in, const int* in_sizes, int n_in,
                              void* d_out, int out_size, void* d_ws, size_t ws_size,
                              hipStream_t stream)
{
    (void)in_sizes; (void)n_in; (void)out_size; (void)ws_size;
    const float* feats = (const float*)d_in[0];
    const float* trans = (const float*)d_in[1];
    float* out = (float*)d_out;

    char* ws = (char*)d_ws;
    size_t off = 0;
    u16*   bp     = (u16*)(ws + off);   off += (size_t)TT*KK*sizeof(u16);    // 64 MB
    u64*   svpT   = (u64*)(ws + off);   off += (size_t)KK*KK*sizeof(u64);    // 2 MB
    float* transT = (float*)(ws + off); off += (size_t)KK*KK*sizeof(float);  // 1 MB
    float* fvBound= (float*)(ws + off); off += (size_t)NSEG*KK*sizeof(float);// 512 KB
    float* fmArr  = (float*)(ws + off); off += (size_t)TT*sizeof(float);     // 256 KB
    u16*   maps   = (u16*)(ws + off);   off += (size_t)NSEG*KK*sizeof(u16);  // 256 KB
    int*   btag   = (int*)(ws + off);   off += (size_t)(NSEG+8)*sizeof(int);
    int*   bestP  = (int*)(ws + off);

    hipLaunchKernelGGL(sort_rows,     dim3(KK),   dim3(512), 0, stream, trans, svpT);
    hipLaunchKernelGGL(transpose_k,   dim3(KK),   dim3(512), 0, stream, trans, transT);
    hipLaunchKernelGGL(fv_scan,       dim3(1),    dim3(512), 0, stream, feats, svpT,
                       transT, fvBound, fmArr, out, bestP);
    hipLaunchKernelGGL(bp_fill,       dim3(NSEG), dim3(512), 0, stream, feats, svpT,
                       fvBound, fmArr, bp);
    hipLaunchKernelGGL(bt_maps,       dim3(NSEG), dim3(512), 0, stream, bp, maps);
    hipLaunchKernelGGL(bt_boundaries, dim3(1),    dim3(64),  0, stream, maps, bestP, btag);
    hipLaunchKernelGGL(bt_decode,     dim3(NSEG), dim3(64),  0, stream, bp, btag, bestP, out + 1);
}